// Round 16
// baseline (24.780 us; speedup 1.0000x reference)
//
#include <hip/hip_runtime.h>
#include <math.h>

#define NROWS 2048
#define DDIM 32

typedef __attribute__((ext_vector_type(8))) short short8;  // 8 bf16
typedef __attribute__((ext_vector_type(4))) float f32x4;
typedef __attribute__((ext_vector_type(2))) float f32x2;

__device__ __forceinline__ unsigned packbf(float a, float b) {
  // bf16(a) in low 16, bf16(b) in high 16 (truncation; lo-plane captures rest)
  return (__float_as_uint(a) >> 16) | (__float_as_uint(b) & 0xffff0000u);
}

// ---------------------------------------------------------------------------
// Single fused kernel. 128x128 tile per 512-thread block (8 waves, 2/SIMD).
// r14 structure + packed-f32 quantum:
//   x-side cs LDS: sCSx[dp*128 + (row ^ (dp&7))] float4 (hc0,hs0,hc1,hs1),
//     x folds ALPHA=0.5.
//   y-side cs LDS (pair-major for v_pk_fma_f32): for col c: g=c>>5,
//     h=(c>>4)&1, p=c&15. Slot (dp*8+2g+b)*16 + (p^dp), b=0: A=(hc0_h0,
//     hc0_h1, hs0_h0, hs0_h1), b=1: B=(same for d+1). One b128 read = packed
//     float2 operands for col-pair (tc, tc+1); zero register repack.
// Order: tile loads -> cs staging -> stats stream (redundant per block,
//   L2-resident) -> reduce -> bf16 hi/lo staging -> MFMA classical ->
//   quantum (packed) -> combine -> store.
// classical = exp(2*dot - nx - ny); quantum term = 0.5 + hcx*cy + hsx*sy.
// ---------------------------------------------------------------------------
__global__ __launch_bounds__(512, 2) void HybridKernel_fused(
    const float* __restrict__ x, const float* __restrict__ y,
    float* __restrict__ out) {
  __shared__ f32x4 sCSx[16 * 128];      // 32 KB x-side cos/sin
  __shared__ f32x4 sYP[2048];           // 32 KB y-side packed cos/sin
  __shared__ uint4 sXB[2][2][128 * 5];  // 40 KB bf16 [side][hi/lo], 80B/row
  __shared__ f32x4 sRed[2][64][8];      // 16 KB stats partials (sum)
  __shared__ f32x4 sRedQ[2][64][8];     // 16 KB stats partials (sumsq)
  __shared__ float sNrm[2][128];
  __shared__ float sMu[2][32];
  __shared__ float sInv[2][32];

  const int t = threadIdx.x;
  const int i0 = blockIdx.y * 128;
  const int j0 = blockIdx.x * 128;

  // --- 1. hoist tile global loads ---
  float4 gx[2], gy[2];
#pragma unroll
  for (int rep = 0; rep < 2; ++rep) {
    const int u = t + 512 * rep;
    const int row = u >> 3;
    const int q = u & 7;
    gx[rep] = *reinterpret_cast<const float4*>(&x[(i0 + row) * DDIM + q * 4]);
    gy[rep] = *reinterpret_cast<const float4*>(&y[(j0 + row) * DDIM + q * 4]);
  }

  // --- 2. cs staging ---
#pragma unroll
  for (int rep = 0; rep < 2; ++rep) {
    const int u = t + 512 * rep;
    const int row = u >> 3;
    const int q = u & 7;
    // x side (fold 0.5)
    {
      const float4 g = gx[rep];
      const float gv[4] = {g.x, g.y, g.z, g.w};
      float hc[4], hs[4];
#pragma unroll
      for (int k = 0; k < 4; ++k) {
        float sn, cs;
        __sincosf(gv[k], &sn, &cs);
        hc[k] = 0.5f * cs;
        hs[k] = 0.5f * sn;
      }
      const int dp0 = 2 * q, dp1 = 2 * q + 1;
      sCSx[dp0 * 128 + (row ^ (dp0 & 7))] = f32x4{hc[0], hs[0], hc[1], hs[1]};
      sCSx[dp1 * 128 + (row ^ (dp1 & 7))] = f32x4{hc[2], hs[2], hc[3], hs[3]};
    }
    // y side (plain), pair-major packed layout
    {
      const float4 g = gy[rep];
      const float gv[4] = {g.x, g.y, g.z, g.w};
      float hc[4], hs[4];
#pragma unroll
      for (int k = 0; k < 4; ++k) {
        float sn, cs;
        __sincosf(gv[k], &sn, &cs);
        hc[k] = cs;
        hs[k] = sn;
      }
      const int gblk = row >> 5;
      const int h = (row >> 4) & 1;
      const int p = row & 15;
#pragma unroll
      for (int e = 0; e < 2; ++e) {
        const int dp = 2 * q + e;
        const int pp = p ^ dp;
        float* bA = (float*)&sYP[(dp * 8 + 2 * gblk + 0) * 16 + pp];
        float* bB = (float*)&sYP[(dp * 8 + 2 * gblk + 1) * 16 + pp];
        bA[h] = hc[2 * e];
        bA[2 + h] = hs[2 * e];
        bB[h] = hc[2 * e + 1];
        bB[2 + h] = hs[2 * e + 1];
      }
    }
  }

  // --- 3. stats streaming (packed) ---
  {
    const int cq = t & 7;
    const int rg = t >> 3;  // 0..63
    const f32x4* px = reinterpret_cast<const f32x4*>(x) + rg * 8 + cq;
    const f32x4* py = reinterpret_cast<const f32x4*>(y) + rg * 8 + cq;
    f32x4 sx = {0.f, 0.f, 0.f, 0.f}, qx = {0.f, 0.f, 0.f, 0.f};
    f32x4 sy = {0.f, 0.f, 0.f, 0.f}, qy = {0.f, 0.f, 0.f, 0.f};
#pragma unroll 4
    for (int i = 0; i < NROWS / 64; ++i) {  // 32 iters
      const f32x4 vx = px[(size_t)i * 64 * 8];
      const f32x4 vy = py[(size_t)i * 64 * 8];
      sx += vx;
      qx = __builtin_elementwise_fma(vx, vx, qx);
      sy += vy;
      qy = __builtin_elementwise_fma(vy, vy, qy);
    }
    sRed[0][rg][cq] = sx;
    sRedQ[0][rg][cq] = qx;
    sRed[1][rg][cq] = sy;
    sRedQ[1][rg][cq] = qy;
  }
  __syncthreads();
  if (t < 128) {
    const int a = t >> 6;
    const int g8 = (t >> 3) & 7;
    const int cq2 = t & 7;
    f32x4 S = {0.f, 0.f, 0.f, 0.f}, Q = {0.f, 0.f, 0.f, 0.f};
#pragma unroll
    for (int k = 0; k < 8; ++k) {
      S += sRed[a][g8 * 8 + k][cq2];
      Q += sRedQ[a][g8 * 8 + k][cq2];
    }
    sRed[a][g8][cq2] = S;
    sRedQ[a][g8][cq2] = Q;
  }
  __syncthreads();
  if (t < 16) {  // t = a*8 + cq
    const int a = t >> 3;
    const int cq2 = t & 7;
    f32x4 S = {0.f, 0.f, 0.f, 0.f}, Q = {0.f, 0.f, 0.f, 0.f};
#pragma unroll
    for (int k = 0; k < 8; ++k) {
      S += sRed[a][k][cq2];
      Q += sRedQ[a][k][cq2];
    }
    const float n = (float)NROWS;
#pragma unroll
    for (int k = 0; k < 4; ++k) {
      const float mean = S[k] / n;
      const float var = fmaxf((Q[k] - S[k] * mean) / (n - 1.f), 0.f);
      sMu[a][cq2 * 4 + k] = mean;
      sInv[a][cq2 * 4 + k] = 1.f / (sqrtf(var) + 1e-8f);
    }
  }
  __syncthreads();

  // --- 4. bf16 hi/lo staging + row norms ---
#pragma unroll
  for (int rep = 0; rep < 2; ++rep) {
    const int u = t + 512 * rep;
    const int row = u >> 3;
    const int q = u & 7;
#pragma unroll
    for (int side = 0; side < 2; ++side) {
      const float4 g = side ? gy[rep] : gx[rep];
      const float gv[4] = {g.x, g.y, g.z, g.w};
      float xn[4];
      float nrm = 0.f;
#pragma unroll
      for (int k = 0; k < 4; ++k) {
        const int d = q * 4 + k;
        xn[k] = (gv[k] - sMu[side][d]) * sInv[side][d];
        nrm = fmaf(xn[k], xn[k], nrm);
      }
      float hif[4], lof[4];
#pragma unroll
      for (int k = 0; k < 4; ++k) {
        hif[k] = __uint_as_float(__float_as_uint(xn[k]) & 0xffff0000u);
        lof[k] = xn[k] - hif[k];
      }
      char* bh = (char*)&sXB[side][0][0] + row * 80 + q * 8;
      char* bl = (char*)&sXB[side][1][0] + row * 80 + q * 8;
      *reinterpret_cast<uint2*>(bh) =
          make_uint2(packbf(hif[0], hif[1]), packbf(hif[2], hif[3]));
      *reinterpret_cast<uint2*>(bl) =
          make_uint2(packbf(lof[0], lof[1]), packbf(lof[2], lof[3]));
      nrm += __shfl_xor(nrm, 1);
      nrm += __shfl_xor(nrm, 2);
      nrm += __shfl_xor(nrm, 4);
      if ((t & 7) == 0) sNrm[side][row] = nrm;
    }
  }
  __syncthreads();

  // --- wave/lane geometry (MFMA C/D layout) ---
  const int w = t >> 6;
  const int l = t & 63;
  const int l4 = l >> 4;  // 0..3
  const int ln = l & 15;
  const int R0 = (w >> 1) * 32;  // wave row base
  const int C0 = (w & 1) * 64;   // wave col base

  int r_idx[8], c_idx[4];
#pragma unroll
  for (int ri = 0; ri < 8; ++ri)
    r_idx[ri] = R0 + 16 * (ri >> 2) + 4 * l4 + (ri & 3);
#pragma unroll
  for (int tc = 0; tc < 4; ++tc) c_idx[tc] = C0 + 16 * tc + ln;

  // --- 5. classical via MFMA: 2x4 tiles, hi/lo 3-pass ---
  short8 Ah[2], Al[2], Bh[4], Bl[4];
  {
    const char* bxh = (const char*)&sXB[0][0][0];
    const char* bxl = (const char*)&sXB[0][1][0];
    const char* byh = (const char*)&sXB[1][0][0];
    const char* byl = (const char*)&sXB[1][1][0];
#pragma unroll
    for (int tr = 0; tr < 2; ++tr) {
      const int off = (R0 + 16 * tr + ln) * 80 + l4 * 16;
      Ah[tr] = *reinterpret_cast<const short8*>(bxh + off);
      Al[tr] = *reinterpret_cast<const short8*>(bxl + off);
    }
#pragma unroll
    for (int tc = 0; tc < 4; ++tc) {
      const int off = (C0 + 16 * tc + ln) * 80 + l4 * 16;
      Bh[tc] = *reinterpret_cast<const short8*>(byh + off);
      Bl[tc] = *reinterpret_cast<const short8*>(byl + off);
    }
  }
  f32x4 dotacc[2][4];
#pragma unroll
  for (int tr = 0; tr < 2; ++tr)
#pragma unroll
    for (int tc = 0; tc < 4; ++tc) {
      f32x4 a = {0.f, 0.f, 0.f, 0.f};
      a = __builtin_amdgcn_mfma_f32_16x16x32_bf16(Ah[tr], Bl[tc], a, 0, 0, 0);
      a = __builtin_amdgcn_mfma_f32_16x16x32_bf16(Al[tr], Bh[tc], a, 0, 0, 0);
      a = __builtin_amdgcn_mfma_f32_16x16x32_bf16(Ah[tr], Bh[tc], a, 0, 0, 0);
      dotacc[tr][tc] = a;
    }

  // --- 6. quantum: 16 phases, packed f32 (v_pk_fma_f32) ---
  const int gBase = C0 >> 5;  // 0 or 2
  f32x2 qp01[8], qp23[8];
#pragma unroll
  for (int ri = 0; ri < 8; ++ri) {
    qp01[ri] = f32x2{1.f, 1.f};
    qp23[ri] = f32x2{1.f, 1.f};
  }

#pragma unroll
  for (int dp = 0; dp < 16; ++dp) {
    const int swx = dp & 7;
    const int pp = ln ^ dp;
    const f32x4 A0 = sYP[(dp * 8 + 2 * gBase + 0) * 16 + pp];
    const f32x4 B0 = sYP[(dp * 8 + 2 * gBase + 1) * 16 + pp];
    const f32x4 A1 = sYP[(dp * 8 + 2 * (gBase + 1) + 0) * 16 + pp];
    const f32x4 B1 = sYP[(dp * 8 + 2 * (gBase + 1) + 1) * 16 + pp];
    const f32x2 h2 = {0.5f, 0.5f};
#pragma unroll
    for (int ri = 0; ri < 8; ++ri) {
      const f32x4 fx = sCSx[dp * 128 + (r_idx[ri] ^ swx)];
      // pair (tc0, tc1)
      f32x2 i0 = __builtin_elementwise_fma(fx.yy, A0.zw, h2);
      f32x2 t0 = __builtin_elementwise_fma(fx.xx, A0.xy, i0);
      f32x2 i1 = __builtin_elementwise_fma(fx.ww, B0.zw, h2);
      f32x2 t1 = __builtin_elementwise_fma(fx.zz, B0.xy, i1);
      qp01[ri] *= t0 * t1;
      // pair (tc2, tc3)
      f32x2 i2 = __builtin_elementwise_fma(fx.yy, A1.zw, h2);
      f32x2 t2 = __builtin_elementwise_fma(fx.xx, A1.xy, i2);
      f32x2 i3 = __builtin_elementwise_fma(fx.ww, B1.zw, h2);
      f32x2 t3 = __builtin_elementwise_fma(fx.zz, B1.xy, i3);
      qp23[ri] *= t2 * t3;
    }
  }

  // --- 7. classical epilogue + combine + store ---
#pragma unroll
  for (int tr = 0; tr < 2; ++tr) {
#pragma unroll
    for (int mm = 0; mm < 4; ++mm) {
      const int ri = tr * 4 + mm;
      const float nx = sNrm[0][r_idx[ri]];
      float* o = out + (size_t)(i0 + r_idx[ri]) * NROWS + j0;
#pragma unroll
      for (int tc = 0; tc < 4; ++tc) {
        const float ny = sNrm[1][c_idx[tc]];
        const float cl = __expf(2.f * dotacc[tr][tc][mm] - nx - ny);
        const float qv = (tc < 2) ? qp01[ri][tc] : qp23[ri][tc - 2];
        o[c_idx[tc]] = 0.5f * (cl + qv);
      }
    }
  }
}

extern "C" void kernel_launch(void* const* d_in, const int* in_sizes, int n_in,
                              void* d_out, int out_size, void* d_ws,
                              size_t ws_size, hipStream_t stream) {
  const float* x = (const float*)d_in[0];
  const float* y = (const float*)d_in[1];
  float* out = (float*)d_out;

  dim3 grid(NROWS / 128, NROWS / 128);
  HybridKernel_fused<<<grid, 512, 0, stream>>>(x, y, out);
}